// Round 8
// baseline (299.536 us; speedup 1.0000x reference)
//
#include <hip/hip_runtime.h>
#include <math.h>

#define C 128
#define SCAN_B 1024

typedef unsigned short ushort_t;
typedef short short8 __attribute__((ext_vector_type(8)));
typedef float floatx4 __attribute__((ext_vector_type(4)));
typedef float fx2 __attribute__((ext_vector_type(2)));

__device__ __forceinline__ ushort_t f2bf(float x) {
  unsigned u = __float_as_uint(x);
  unsigned r = (u + 0x7FFFu + ((u >> 16) & 1u)) >> 16;
  return (ushort_t)r;
}
__device__ __forceinline__ fx2 bf2f2(unsigned u) {
  fx2 r;
  r.x = __uint_as_float(u << 16);
  r.y = __uint_as_float(u & 0xFFFF0000u);
  return r;
}

// ---------------- init ----------------

__global__ void init_ws(int* __restrict__ deg, float* __restrict__ lossacc, int n) {
  int i = blockIdx.x * blockDim.x + threadIdx.x;
  if (i < n) deg[i] = 0;
  if (i == 0) lossacc[0] = 0.f;
}

// ---------------- CSR build (sort edges by dst) ----------------

__global__ void hist_kernel(const int* __restrict__ ei, int* __restrict__ deg,
                            int* __restrict__ pos, int E, int ET) {
  int e = blockIdx.x * blockDim.x + threadIdx.x;
  if (e >= ET) return;
  int d = (e < E) ? ei[E + e] : (e - E);   // self loop dst = node id
  pos[e] = atomicAdd(&deg[d], 1);
}

__global__ void scan_block(const int* __restrict__ deg, int* __restrict__ row_ptr,
                           int* __restrict__ bsums, int n) {
  __shared__ int sh[SCAN_B];
  int tid = threadIdx.x;
  int i = blockIdx.x * SCAN_B + tid;
  int v = (i < n) ? deg[i] : 0;
  sh[tid] = v;
  __syncthreads();
  #pragma unroll
  for (int off = 1; off < SCAN_B; off <<= 1) {
    int t = (tid >= off) ? sh[tid - off] : 0;
    __syncthreads();
    sh[tid] += t;
    __syncthreads();
  }
  if (i < n) row_ptr[i] = sh[tid] - v;          // block-local exclusive
  if (tid == SCAN_B - 1) bsums[blockIdx.x] = sh[tid];
}

__global__ void scan_sums(int* __restrict__ bsums, int nb) {
  int lane = threadIdx.x;
  int v = (lane < nb) ? bsums[lane] : 0;
  int orig = v;
  #pragma unroll
  for (int off = 1; off < 64; off <<= 1) {
    int t = __shfl_up(v, off);
    if (lane >= off) v += t;
  }
  if (lane < nb) bsums[lane] = v - orig;        // exclusive
  if (lane == 63) bsums[nb] = v;                // total
}

__global__ void scan_add(int* __restrict__ row_ptr, const int* __restrict__ bsums, int n, int nb) {
  int i = blockIdx.x * blockDim.x + threadIdx.x;
  if (i < n) row_ptr[i] += bsums[i >> 10];
  if (i == 0) row_ptr[n] = bsums[nb];
}

// no atomics: position precomputed by hist_kernel; also writes dst per slot
__global__ void scatter_kernel(const int* __restrict__ ei, const int* __restrict__ row_ptr,
                               const int* __restrict__ pos, int* __restrict__ col,
                               int* __restrict__ dstc, int E, int ET) {
  int e = blockIdx.x * blockDim.x + threadIdx.x;
  if (e >= ET) return;
  int s = (e < E) ? ei[e] : (e - E);
  int d = (e < E) ? ei[E + e] : (e - E);
  int slot = row_ptr[d] + pos[e];
  col[slot] = s;
  dstc[slot] = d;
}

// ---------------- weight prep: transpose + bf16 ----------------

__global__ void prep_weights(const float* __restrict__ Wl, const float* __restrict__ Wr,
                             const float* __restrict__ W1,
                             ushort_t* __restrict__ wcat, ushort_t* __restrict__ w1t) {
  int idx = blockIdx.x * blockDim.x + threadIdx.x;
  const int NCAT = 2 * 256 * 128;
  if (idx < NCAT) {
    int l = idx >> 15;           // /32768
    int rem = idx & 32767;
    int n = rem >> 7;
    int k = rem & 127;
    float v = (n < 128) ? Wl[l * C * C + k * C + n] : Wr[l * C * C + k * C + (n - 128)];
    wcat[idx] = f2bf(v);
  } else {
    int j = idx - NCAT;          // w1t index
    if (j < 128 * 256) {
      int n = j >> 8;
      int k = j & 255;
      w1t[j] = f2bf(W1[k * C + n]);
    }
  }
}

__global__ void convert_x(const float* __restrict__ x, ushort_t* __restrict__ xb, int total4) {
  int i = blockIdx.x * blockDim.x + threadIdx.x;
  if (i >= total4) return;
  float4 v = ((const float4*)x)[i];
  ushort4 s;
  s.x = f2bf(v.x); s.y = f2bf(v.y); s.z = f2bf(v.z); s.w = f2bf(v.w);
  ((ushort4*)xb)[i] = s;
}

// ---------------- bf16 MFMA GEMM ----------------

__global__ __launch_bounds__(256) void gemm_mfma(
    const ushort_t* __restrict__ A, const ushort_t* __restrict__ Bt,
    int M, int K,
    ushort_t* __restrict__ outb0, ushort_t* __restrict__ outb1,
    float* __restrict__ outf, const float* __restrict__ bias, int do_relu) {
  int tid = threadIdx.x;
  int wave = tid >> 6, lane = tid & 63;
  int wm = (wave >> 1) * 64, wn = (wave & 1) * 64;
  int m_base = blockIdx.x * 128 + wm;
  int lrow = lane & 15, lkg = lane >> 4;

  floatx4 acc[4][4];
  #pragma unroll
  for (int mi = 0; mi < 4; mi++)
    #pragma unroll
    for (int ni = 0; ni < 4; ni++)
      acc[mi][ni] = (floatx4){0.f, 0.f, 0.f, 0.f};

  const int ksteps = K >> 5;
  for (int ks = 0; ks < ksteps; ks++) {
    int koff = ks * 32 + lkg * 8;
    short8 af[4], bfr[4];
    #pragma unroll
    for (int mi = 0; mi < 4; mi++) {
      int gm = m_base + mi * 16 + lrow;
      gm = (gm < M) ? gm : (M - 1);
      af[mi] = *(const short8*)&A[(size_t)gm * K + koff];
    }
    #pragma unroll
    for (int ni = 0; ni < 4; ni++) {
      int gn = blockIdx.y * 128 + wn + ni * 16 + lrow;
      bfr[ni] = *(const short8*)&Bt[(size_t)gn * K + koff];
    }
    #pragma unroll
    for (int mi = 0; mi < 4; mi++)
      #pragma unroll
      for (int ni = 0; ni < 4; ni++)
        acc[mi][ni] = __builtin_amdgcn_mfma_f32_16x16x32_bf16(af[mi], bfr[ni], acc[mi][ni], 0, 0, 0);
  }

  ushort_t* outb = (blockIdx.y == 0) ? outb0 : outb1;
  #pragma unroll
  for (int mi = 0; mi < 4; mi++) {
    #pragma unroll
    for (int r = 0; r < 4; r++) {
      int gm = m_base + mi * 16 + lkg * 4 + r;
      if (gm >= M) continue;
      #pragma unroll
      for (int ni = 0; ni < 4; ni++) {
        int nl = wn + ni * 16 + lrow;         // 0..127 within this by's output
        float v = acc[mi][ni][r];
        if (outf) {
          if (bias) v += bias[nl];
          if (do_relu) v = fmaxf(v, 0.f);
          outf[(size_t)gm * 128 + nl] = v;
        } else {
          outb[(size_t)gm * 128 + nl] = f2bf(v);
        }
      }
    }
  }
}

// ---------------- pass A: per-edge logits over CSR slots ----------------
// Uniform streaming over ET slots: wave = 4 groups x 16 lanes; each group
// computes 2 edges (slots wv*8+g and wv*8+4+g). pe = exp(a . leaky(xl+xr)).
// No per-node raggedness, no loop-carried state; xr/att reads are L1-hot.

__global__ void edge_logits(const ushort_t* __restrict__ xl, const ushort_t* __restrict__ xr,
                            const int* __restrict__ col, const int* __restrict__ dstc,
                            const float* __restrict__ att, float* __restrict__ pec, int ET) {
  int wv = (int)((blockIdx.x * (size_t)blockDim.x + threadIdx.x) >> 6);
  int lane = threadIdx.x & 63;
  int g = lane >> 4, p = lane & 15;
  int c0 = p * 8;
  int s0 = wv * 8 + g;
  int s1 = s0 + 4;
  if (s0 >= ET) return;
  bool A1 = s1 < ET;

  fx2 av[4];
  {
    float4 a0 = *(const float4*)&att[c0];
    float4 a1 = *(const float4*)&att[c0 + 4];
    av[0] = (fx2){a0.x, a0.y}; av[1] = (fx2){a0.z, a0.w};
    av[2] = (fx2){a1.x, a1.y}; av[3] = (fx2){a1.z, a1.w};
  }

  int j0 = col[s0];
  int d0 = dstc[s0];
  int j1 = col[A1 ? s1 : s0];
  int d1 = dstc[A1 ? s1 : s0];
  uint4 rl0 = *(const uint4*)&xl[((size_t)j0 << 7) + c0];
  uint4 rr0 = *(const uint4*)&xr[((size_t)d0 << 7) + c0];
  uint4 rl1 = *(const uint4*)&xl[((size_t)j1 << 7) + c0];
  uint4 rr1 = *(const uint4*)&xr[((size_t)d1 << 7) + c0];

  fx2 d0s = (fx2){0.f, 0.f}, d1s = (fx2){0.f, 0.f};
  {
    fx2 zl, zr, z;
    zl = bf2f2(rl0.x); zr = bf2f2(rr0.x); z = zl + zr;
    z = __builtin_elementwise_max(z, z * 0.2f); d0s = __builtin_elementwise_fma(z, av[0], d0s);
    zl = bf2f2(rl0.y); zr = bf2f2(rr0.y); z = zl + zr;
    z = __builtin_elementwise_max(z, z * 0.2f); d0s = __builtin_elementwise_fma(z, av[1], d0s);
    zl = bf2f2(rl0.z); zr = bf2f2(rr0.z); z = zl + zr;
    z = __builtin_elementwise_max(z, z * 0.2f); d0s = __builtin_elementwise_fma(z, av[2], d0s);
    zl = bf2f2(rl0.w); zr = bf2f2(rr0.w); z = zl + zr;
    z = __builtin_elementwise_max(z, z * 0.2f); d0s = __builtin_elementwise_fma(z, av[3], d0s);

    zl = bf2f2(rl1.x); zr = bf2f2(rr1.x); z = zl + zr;
    z = __builtin_elementwise_max(z, z * 0.2f); d1s = __builtin_elementwise_fma(z, av[0], d1s);
    zl = bf2f2(rl1.y); zr = bf2f2(rr1.y); z = zl + zr;
    z = __builtin_elementwise_max(z, z * 0.2f); d1s = __builtin_elementwise_fma(z, av[1], d1s);
    zl = bf2f2(rl1.z); zr = bf2f2(rr1.z); z = zl + zr;
    z = __builtin_elementwise_max(z, z * 0.2f); d1s = __builtin_elementwise_fma(z, av[2], d1s);
    zl = bf2f2(rl1.w); zr = bf2f2(rr1.w); z = zl + zr;
    z = __builtin_elementwise_max(z, z * 0.2f); d1s = __builtin_elementwise_fma(z, av[3], d1s);
  }
  float p0 = d0s.x + d0s.y;
  float p1 = d1s.x + d1s.y;
  #pragma unroll
  for (int off = 1; off <= 8; off <<= 1) {
    p0 += __shfl_xor(p0, off);
    p1 += __shfl_xor(p1, off);
  }
  if (p == 0) {
    pec[s0] = __expf(p0);
    if (A1) pec[s1] = __expf(p1);
  }
}

// ---------------- pass B: weighted aggregation (PV) ----------------
// One wave per dst node; 4 groups x 16 lanes x 2 edges/iter. No logit math,
// no exp, no shuffles in the loop (only the final group combine).

__global__ void gat_pv(const ushort_t* __restrict__ xl,
                       const int* __restrict__ row_ptr, const int* __restrict__ col,
                       const float* __restrict__ pec, const float* __restrict__ bias,
                       float* __restrict__ houtf, ushort_t* __restrict__ houtb,
                       int n, int do_relu) {
  int wid = (int)((blockIdx.x * (size_t)blockDim.x + threadIdx.x) >> 6);
  int lane = threadIdx.x & 63;
  if (wid >= n) return;
  int g = lane >> 4, p = lane & 15;
  int c0 = p * 8;
  const size_t i = wid;

  int beg = row_ptr[wid], end = row_ptr[wid + 1];
  float denom = 0.f;
  fx2 acc[4];
  #pragma unroll
  for (int q = 0; q < 4; q++) acc[q] = (fx2){0.f, 0.f};

  for (int base = beg; base < end; base += 8) {
    int e0 = base + g;
    int e1 = e0 + 4;
    bool a0 = e0 < end, a1 = e1 < end;
    int j0 = col[a0 ? e0 : beg];
    int j1 = col[a1 ? e1 : beg];
    float pe0 = a0 ? pec[e0] : 0.f;
    float pe1 = a1 ? pec[e1] : 0.f;
    uint4 r0 = *(const uint4*)&xl[((size_t)j0 << 7) + c0];
    uint4 r1 = *(const uint4*)&xl[((size_t)j1 << 7) + c0];
    denom += pe0 + pe1;
    fx2 v0 = (fx2){pe0, pe0}, v1 = (fx2){pe1, pe1};
    acc[0] = __builtin_elementwise_fma(v0, bf2f2(r0.x), acc[0]);
    acc[1] = __builtin_elementwise_fma(v0, bf2f2(r0.y), acc[1]);
    acc[2] = __builtin_elementwise_fma(v0, bf2f2(r0.z), acc[2]);
    acc[3] = __builtin_elementwise_fma(v0, bf2f2(r0.w), acc[3]);
    acc[0] = __builtin_elementwise_fma(v1, bf2f2(r1.x), acc[0]);
    acc[1] = __builtin_elementwise_fma(v1, bf2f2(r1.y), acc[1]);
    acc[2] = __builtin_elementwise_fma(v1, bf2f2(r1.z), acc[2]);
    acc[3] = __builtin_elementwise_fma(v1, bf2f2(r1.w), acc[3]);
  }

  #pragma unroll
  for (int off = 16; off <= 32; off <<= 1) {
    denom += __shfl_xor(denom, off);
    #pragma unroll
    for (int q = 0; q < 4; q++) {
      acc[q].x += __shfl_xor(acc[q].x, off);
      acc[q].y += __shfl_xor(acc[q].y, off);
    }
  }

  if (g == 0) {
    float inv = 1.f / denom;            // degree >= 1 via self loop
    float4 b0 = *(const float4*)&bias[c0];
    float4 b1 = *(const float4*)&bias[c0 + 4];
    float o[8];
    o[0] = acc[0].x*inv + b0.x; o[1] = acc[0].y*inv + b0.y;
    o[2] = acc[1].x*inv + b0.z; o[3] = acc[1].y*inv + b0.w;
    o[4] = acc[2].x*inv + b1.x; o[5] = acc[2].y*inv + b1.y;
    o[6] = acc[3].x*inv + b1.z; o[7] = acc[3].y*inv + b1.w;
    if (do_relu) {
      #pragma unroll
      for (int c = 0; c < 8; c++) o[c] = fmaxf(o[c], 0.f);
    }
    if (houtf) {
      *(float4*)&houtf[i * C + c0]     = make_float4(o[0], o[1], o[2], o[3]);
      *(float4*)&houtf[i * C + c0 + 4] = make_float4(o[4], o[5], o[6], o[7]);
    } else {
      short8 s;
      #pragma unroll
      for (int c = 0; c < 8; c++) s[c] = (short)f2bf(o[c]);
      *(short8*)&houtb[i * C + c0] = s;
    }
  }
}

// ---------------- scorer ----------------

__global__ void gather_pairs(const float* __restrict__ h, const int* __restrict__ tp,
                             const int* __restrict__ fp, float4* __restrict__ out,
                             ushort_t* __restrict__ outbf, int P2) {
  int idx = blockIdx.x * blockDim.x + threadIdx.x;   // float4 index over [2P][256/4]
  if (idx >= P2 * 64) return;
  int r = idx >> 6, c4 = idx & 63;
  int half = P2 >> 1;
  const int* pairs = (r < half) ? tp : fp;
  int rr = (r < half) ? r : r - half;
  int node = pairs[rr * 2 + (c4 >= 32 ? 1 : 0)];
  float4 v = *(const float4*)&h[(size_t)node * C + (c4 & 31) * 4];
  out[idx] = v;
  ushort4 s;
  s.x = f2bf(v.x); s.y = f2bf(v.y); s.z = f2bf(v.z); s.w = f2bf(v.w);
  *(ushort4*)&outbf[(size_t)idx * 4] = s;
}

__global__ __launch_bounds__(256) void probs_loss(
    const float* __restrict__ hid, const float* __restrict__ W2,
    const float* __restrict__ b2, float* __restrict__ probs_out,
    float* __restrict__ lossacc, int rows, int P) {
  __shared__ float red[256];
  int tid = threadIdx.x;
  int r = blockIdx.x * blockDim.x + tid;
  float term = 0.f;
  if (r < rows) {
    const float4* hp = (const float4*)&hid[(size_t)r * C];
    const float4* wp = (const float4*)W2;
    float s = 0.f;
    #pragma unroll
    for (int i = 0; i < 32; i++) {
      float4 h4 = hp[i], w4 = wp[i];
      s += h4.x * w4.x + h4.y * w4.y + h4.z * w4.z + h4.w * w4.w;
    }
    s += b2[0];
    float p = 1.f / (1.f + expf(-s));
    probs_out[r] = p;
    float pcl = fminf(fmaxf(p, 1e-7f), 1.f - 1e-7f);
    term = (r < P) ? logf(pcl) : log1pf(-pcl);
  }
  red[tid] = term;
  __syncthreads();
  #pragma unroll
  for (int off = 128; off >= 1; off >>= 1) {
    if (tid < off) red[tid] += red[tid + off];
    __syncthreads();
  }
  if (tid == 0) atomicAdd(lossacc, red[0]);
}

__global__ void finalize_loss(const float* __restrict__ lossacc, float* __restrict__ out, int rows) {
  out[0] = -lossacc[0] / (float)rows;
}

// ---------------- launch ----------------

extern "C" void kernel_launch(void* const* d_in, const int* in_sizes, int n_in,
                              void* d_out, int out_size, void* d_ws, size_t ws_size,
                              hipStream_t stream) {
  const float* x    = (const float*)d_in[0];
  const int*   ei   = (const int*)d_in[1];
  const int*   tp   = (const int*)d_in[2];
  const int*   fp   = (const int*)d_in[3];
  const float* Wl   = (const float*)d_in[4];
  const float* Wr   = (const float*)d_in[5];
  const float* att  = (const float*)d_in[6];
  const float* bias = (const float*)d_in[7];
  const float* W1   = (const float*)d_in[8];
  const float* b1   = (const float*)d_in[9];
  const float* W2   = (const float*)d_in[10];
  const float* b2   = (const float*)d_in[11];

  int N  = in_sizes[0] / C;    // 50000
  int E  = in_sizes[1] / 2;    // 800000
  int P  = in_sizes[2] / 2;    // 8192
  int ET = E + N;
  int P2 = 2 * P;
  int nb = (N + SCAN_B - 1) / SCAN_B;   // scan blocks (49)

  float* out       = (float*)d_out;
  float* out_pos   = out;                                  // [2P, 2C] (pos then neg)
  float* out_probs = out + (size_t)P2 * 2 * C;
  float* out_loss  = out_probs + P2;

  char* w = (char*)d_ws;
  size_t NCb2 = (size_t)N * C * 2;                         // bf16 [N,C]
  ushort_t* x_bf  = (ushort_t*)w;  w += NCb2;
  ushort_t* xl_bf = (ushort_t*)w;  w += NCb2;
  ushort_t* xr_bf = (ushort_t*)w;  w += NCb2;
  ushort_t* h1_bf = (ushort_t*)w;  w += NCb2;
  float* h1f = (float*)w;          w += (size_t)N * C * 4;
  ushort_t* pairs_bf = (ushort_t*)w; w += (size_t)P2 * 2 * C * 2;
  float* hid = (float*)w;          w += (size_t)P2 * C * 4;
  ushort_t* wcat = (ushort_t*)w;   w += (size_t)2 * 256 * 128 * 2;
  ushort_t* w1t  = (ushort_t*)w;   w += (size_t)128 * 256 * 2;
  int* deg     = (int*)w;  w += (size_t)N * 4;
  int* row_ptr = (int*)w;  w += (size_t)(N + 1) * 4 + 12;  // keep next aligned
  int* pos     = (int*)w;  w += (size_t)ET * 4;
  int* col     = (int*)w;  w += (size_t)ET * 4;
  int* dstc    = (int*)w;  w += (size_t)ET * 4;
  float* pec   = (float*)w; w += (size_t)ET * 4;
  int* bsums   = (int*)w;  w += (size_t)(nb + 1) * 4 + 8;
  float* lossacc = (float*)w;

  const int tB = 256;
  init_ws<<<(N + tB - 1) / tB, tB, 0, stream>>>(deg, lossacc, N);
  prep_weights<<<384, tB, 0, stream>>>(Wl, Wr, W1, wcat, w1t);
  convert_x<<<(N * C / 4 + tB - 1) / tB, tB, 0, stream>>>(x, x_bf, N * C / 4);

  hist_kernel<<<(ET + tB - 1) / tB, tB, 0, stream>>>(ei, deg, pos, E, ET);
  scan_block<<<nb, SCAN_B, 0, stream>>>(deg, row_ptr, bsums, N);
  scan_sums<<<1, 64, 0, stream>>>(bsums, nb);
  scan_add<<<(N + SCAN_B - 1) / SCAN_B, SCAN_B, 0, stream>>>(row_ptr, bsums, N, nb);
  scatter_kernel<<<(ET + tB - 1) / tB, tB, 0, stream>>>(ei, row_ptr, pos, col, dstc, E, ET);

  int gblk = (N + 127) / 128;
  int lgblk = ((ET + 7) / 8 + 3) / 4;   // edge_logits blocks: 4 waves x 8 slots

  // layer 0
  gemm_mfma<<<dim3(gblk, 2), tB, 0, stream>>>(
      x_bf, wcat, N, C, xl_bf, xr_bf, nullptr, nullptr, 0);
  edge_logits<<<lgblk, tB, 0, stream>>>(xl_bf, xr_bf, col, dstc, att, pec, ET);
  gat_pv<<<(N * 64 + tB - 1) / tB, tB, 0, stream>>>(
      xl_bf, row_ptr, col, pec, bias, nullptr, h1_bf, N, 1);

  // layer 1
  gemm_mfma<<<dim3(gblk, 2), tB, 0, stream>>>(
      h1_bf, wcat + (size_t)256 * 128, N, C, xl_bf, xr_bf, nullptr, nullptr, 0);
  edge_logits<<<lgblk, tB, 0, stream>>>(xl_bf, xr_bf, col, dstc, att + C, pec, ET);
  gat_pv<<<(N * 64 + tB - 1) / tB, tB, 0, stream>>>(
      xl_bf, row_ptr, col, pec, bias + C, h1f, nullptr, N, 0);

  gather_pairs<<<(P2 * 64 + tB - 1) / tB, tB, 0, stream>>>(h1f, tp, fp, (float4*)out_pos, pairs_bf, P2);
  gemm_mfma<<<dim3(P2 / 128, 1), tB, 0, stream>>>(
      pairs_bf, w1t, P2, 2 * C, nullptr, nullptr, hid, b1, 1);
  probs_loss<<<(P2 + tB - 1) / tB, tB, 0, stream>>>(hid, W2, b2, out_probs, lossacc, P2, P);
  finalize_loss<<<1, 1, 0, stream>>>(lossacc, out_loss, P2);
}

// Round 9
// 236.042 us; speedup vs baseline: 1.2690x; 1.2690x over previous
//
#include <hip/hip_runtime.h>
#include <math.h>

#define C 128
#define SCAN_B 1024

typedef unsigned short ushort_t;
typedef short short8 __attribute__((ext_vector_type(8)));
typedef float floatx4 __attribute__((ext_vector_type(4)));
typedef float fx2 __attribute__((ext_vector_type(2)));

__device__ __forceinline__ ushort_t f2bf(float x) {
  unsigned u = __float_as_uint(x);
  unsigned r = (u + 0x7FFFu + ((u >> 16) & 1u)) >> 16;
  return (ushort_t)r;
}
__device__ __forceinline__ fx2 bf2f2(unsigned u) {
  fx2 r;
  r.x = __uint_as_float(u << 16);
  r.y = __uint_as_float(u & 0xFFFF0000u);
  return r;
}

// ---------------- K0: init ws + weight prep (independent) ----------------

__global__ void k_init_prep(int* __restrict__ deg, float* __restrict__ lossacc, int n,
                            const float* __restrict__ Wl, const float* __restrict__ Wr,
                            const float* __restrict__ W1,
                            ushort_t* __restrict__ wcat, ushort_t* __restrict__ w1t) {
  int idx = blockIdx.x * blockDim.x + threadIdx.x;
  if (idx < n) deg[idx] = 0;
  if (idx == 0) lossacc[0] = 0.f;
  const int NCAT = 2 * 256 * 128;
  if (idx < NCAT) {
    int l = idx >> 15;
    int rem = idx & 32767;
    int nn = rem >> 7;
    int k = rem & 127;
    float v = (nn < 128) ? Wl[l * C * C + k * C + nn] : Wr[l * C * C + k * C + (nn - 128)];
    wcat[idx] = f2bf(v);
  } else if (idx < NCAT + 128 * 256) {
    int j = idx - NCAT;
    int nn = j >> 8;
    int k = j & 255;
    w1t[j] = f2bf(W1[k * C + nn]);
  }
}

// ---------------- K1: convert x to bf16 + histogram (independent) ----------------

__global__ void k_conv_hist(const float* __restrict__ x, ushort_t* __restrict__ xb, int total4,
                            const int* __restrict__ ei, int* __restrict__ deg,
                            int* __restrict__ pos, int E, int ET) {
  int i = blockIdx.x * blockDim.x + threadIdx.x;
  if (i < total4) {
    float4 v = ((const float4*)x)[i];
    ushort4 s;
    s.x = f2bf(v.x); s.y = f2bf(v.y); s.z = f2bf(v.z); s.w = f2bf(v.w);
    ((ushort4*)xb)[i] = s;
  }
  if (i < ET) {
    int d = (i < E) ? ei[E + i] : (i - E);   // self loop dst = node id
    pos[i] = atomicAdd(&deg[d], 1);
  }
}

// ---------------- scan ----------------

__global__ void scan_block(const int* __restrict__ deg, int* __restrict__ row_ptr,
                           int* __restrict__ bsums, int n) {
  __shared__ int sh[SCAN_B];
  int tid = threadIdx.x;
  int i = blockIdx.x * SCAN_B + tid;
  int v = (i < n) ? deg[i] : 0;
  sh[tid] = v;
  __syncthreads();
  #pragma unroll
  for (int off = 1; off < SCAN_B; off <<= 1) {
    int t = (tid >= off) ? sh[tid - off] : 0;
    __syncthreads();
    sh[tid] += t;
    __syncthreads();
  }
  if (i < n) row_ptr[i] = sh[tid] - v;          // block-local exclusive
  if (tid == SCAN_B - 1) bsums[blockIdx.x] = sh[tid];
}

__global__ void scan_sums(int* __restrict__ bsums, int nb) {
  int lane = threadIdx.x;
  int v = (lane < nb) ? bsums[lane] : 0;
  int orig = v;
  #pragma unroll
  for (int off = 1; off < 64; off <<= 1) {
    int t = __shfl_up(v, off);
    if (lane >= off) v += t;
  }
  if (lane < nb) bsums[lane] = v - orig;        // exclusive
  if (lane == 63) bsums[nb] = v;                // total
}

__global__ void scan_add(int* __restrict__ row_ptr, const int* __restrict__ bsums, int n, int nb) {
  int i = blockIdx.x * blockDim.x + threadIdx.x;
  if (i < n) row_ptr[i] += bsums[i >> 10];
  if (i == 0) row_ptr[n] = bsums[nb];
}

// ---------------- bf16 MFMA GEMM body (shared) ----------------

__device__ __forceinline__ void gemm_body(
    const ushort_t* __restrict__ A, const ushort_t* __restrict__ Bt,
    int M, int K,
    ushort_t* __restrict__ outb0, ushort_t* __restrict__ outb1,
    float* __restrict__ outf, const float* __restrict__ bias, int do_relu,
    int bx, int by) {
  int tid = threadIdx.x;
  int wave = tid >> 6, lane = tid & 63;
  int wm = (wave >> 1) * 64, wn = (wave & 1) * 64;
  int m_base = bx * 128 + wm;
  int lrow = lane & 15, lkg = lane >> 4;

  floatx4 acc[4][4];
  #pragma unroll
  for (int mi = 0; mi < 4; mi++)
    #pragma unroll
    for (int ni = 0; ni < 4; ni++)
      acc[mi][ni] = (floatx4){0.f, 0.f, 0.f, 0.f};

  const int ksteps = K >> 5;
  for (int ks = 0; ks < ksteps; ks++) {
    int koff = ks * 32 + lkg * 8;
    short8 af[4], bfr[4];
    #pragma unroll
    for (int mi = 0; mi < 4; mi++) {
      int gm = m_base + mi * 16 + lrow;
      gm = (gm < M) ? gm : (M - 1);
      af[mi] = *(const short8*)&A[(size_t)gm * K + koff];
    }
    #pragma unroll
    for (int ni = 0; ni < 4; ni++) {
      int gn = by * 128 + wn + ni * 16 + lrow;
      bfr[ni] = *(const short8*)&Bt[(size_t)gn * K + koff];
    }
    #pragma unroll
    for (int mi = 0; mi < 4; mi++)
      #pragma unroll
      for (int ni = 0; ni < 4; ni++)
        acc[mi][ni] = __builtin_amdgcn_mfma_f32_16x16x32_bf16(af[mi], bfr[ni], acc[mi][ni], 0, 0, 0);
  }

  ushort_t* outb = (by == 0) ? outb0 : outb1;
  #pragma unroll
  for (int mi = 0; mi < 4; mi++) {
    #pragma unroll
    for (int r = 0; r < 4; r++) {
      int gm = m_base + mi * 16 + lkg * 4 + r;
      if (gm >= M) continue;
      #pragma unroll
      for (int ni = 0; ni < 4; ni++) {
        int nl = wn + ni * 16 + lrow;
        float v = acc[mi][ni][r];
        if (outf) {
          if (bias) v += bias[nl];
          if (do_relu) v = fmaxf(v, 0.f);
          outf[(size_t)gm * 128 + nl] = v;
        } else {
          outb[(size_t)gm * 128 + nl] = f2bf(v);
        }
      }
    }
  }
}

__global__ __launch_bounds__(256) void gemm_mfma(
    const ushort_t* __restrict__ A, const ushort_t* __restrict__ Bt,
    int M, int K,
    ushort_t* __restrict__ outb0, ushort_t* __restrict__ outb1,
    float* __restrict__ outf, const float* __restrict__ bias, int do_relu) {
  gemm_body(A, Bt, M, K, outb0, outb1, outf, bias, do_relu, blockIdx.x, blockIdx.y);
}

// ---------------- K2: gemm layer-0 ∪ scatter (both ready after scans) ----------------

__global__ __launch_bounds__(256) void k_gemm_scatter(
    const ushort_t* __restrict__ A, const ushort_t* __restrict__ Bt,
    int M, int K,
    ushort_t* __restrict__ outb0, ushort_t* __restrict__ outb1, int gb,
    const int* __restrict__ ei, const int* __restrict__ row_ptr,
    const int* __restrict__ pos, int* __restrict__ col, int E, int ET) {
  int bx = blockIdx.x;
  if (bx < gb) {
    gemm_body(A, Bt, M, K, outb0, outb1, nullptr, nullptr, 0, bx, blockIdx.y);
  } else {
    int chunk = (bx - gb) * 2 + blockIdx.y;
    int e = chunk * 256 + threadIdx.x;
    if (e < ET) {
      int s = (e < E) ? ei[e] : (e - E);
      int d = (e < E) ? ei[E + e] : (e - E);
      col[row_ptr[d] + pos[e]] = s;
    }
  }
}

// ---------------- GATv2 fused edge softmax + aggregation (round-6 version) ----------------

__global__ __launch_bounds__(256) void gat_aggregate(
    const ushort_t* __restrict__ xl, const ushort_t* __restrict__ xr,
    const int* __restrict__ row_ptr, const int* __restrict__ col,
    const float* __restrict__ att, const float* __restrict__ bias,
    float* __restrict__ houtf, ushort_t* __restrict__ houtb,
    int n, int do_relu) {
  int wid = (int)((blockIdx.x * (size_t)blockDim.x + threadIdx.x) >> 6);
  int lane = threadIdx.x & 63;
  if (wid >= n) return;
  int g = lane >> 4, p = lane & 15;
  int c0 = p * 8;
  const size_t i = wid;

  fx2 xri[4], av[4];
  {
    uint4 ur = *(const uint4*)&xr[i * C + c0];
    xri[0] = bf2f2(ur.x); xri[1] = bf2f2(ur.y);
    xri[2] = bf2f2(ur.z); xri[3] = bf2f2(ur.w);
    float4 a0 = *(const float4*)&att[c0];
    float4 a1 = *(const float4*)&att[c0 + 4];
    av[0] = (fx2){a0.x, a0.y}; av[1] = (fx2){a0.z, a0.w};
    av[2] = (fx2){a1.x, a1.y}; av[3] = (fx2){a1.z, a1.w};
  }

  int beg = row_ptr[wid], end = row_ptr[wid + 1];
  float denom = 0.f;
  fx2 acc[4];
  #pragma unroll
  for (int q = 0; q < 4; q++) acc[q] = (fx2){0.f, 0.f};

  for (int base = beg; base < end; base += 8) {
    int e0 = base + g;
    int e1 = e0 + 4;
    bool a0 = e0 < end, a1 = e1 < end;
    int j0 = col[a0 ? e0 : beg];
    int j1 = col[a1 ? e1 : beg];
    uint4 r0 = *(const uint4*)&xl[((size_t)j0 << 7) + c0];
    uint4 r1 = *(const uint4*)&xl[((size_t)j1 << 7) + c0];
    fx2 x0[4], x1[4];
    x0[0] = bf2f2(r0.x); x0[1] = bf2f2(r0.y); x0[2] = bf2f2(r0.z); x0[3] = bf2f2(r0.w);
    x1[0] = bf2f2(r1.x); x1[1] = bf2f2(r1.y); x1[2] = bf2f2(r1.z); x1[3] = bf2f2(r1.w);

    fx2 d0 = (fx2){0.f, 0.f}, d1 = (fx2){0.f, 0.f};
    #pragma unroll
    for (int q = 0; q < 4; q++) {
      fx2 z0 = x0[q] + xri[q];
      fx2 z1 = x1[q] + xri[q];
      z0 = __builtin_elementwise_max(z0, z0 * 0.2f);
      z1 = __builtin_elementwise_max(z1, z1 * 0.2f);
      d0 = __builtin_elementwise_fma(z0, av[q], d0);
      d1 = __builtin_elementwise_fma(z1, av[q], d1);
    }
    float p0 = d0.x + d0.y;
    float p1 = d1.x + d1.y;
    #pragma unroll
    for (int off = 1; off <= 8; off <<= 1) {
      p0 += __shfl_xor(p0, off);
      p1 += __shfl_xor(p1, off);
    }
    float pe0 = a0 ? __expf(p0) : 0.f;
    float pe1 = a1 ? __expf(p1) : 0.f;
    denom += pe0 + pe1;
    fx2 v0 = (fx2){pe0, pe0}, v1 = (fx2){pe1, pe1};
    #pragma unroll
    for (int q = 0; q < 4; q++) {
      acc[q] = __builtin_elementwise_fma(v0, x0[q], acc[q]);
      acc[q] = __builtin_elementwise_fma(v1, x1[q], acc[q]);
    }
  }

  #pragma unroll
  for (int off = 16; off <= 32; off <<= 1) {
    denom += __shfl_xor(denom, off);
    #pragma unroll
    for (int q = 0; q < 4; q++) {
      acc[q].x += __shfl_xor(acc[q].x, off);
      acc[q].y += __shfl_xor(acc[q].y, off);
    }
  }

  if (g == 0) {
    float inv = 1.f / denom;            // degree >= 1 via self loop
    float4 b0 = *(const float4*)&bias[c0];
    float4 b1 = *(const float4*)&bias[c0 + 4];
    float o[8];
    o[0] = acc[0].x*inv + b0.x; o[1] = acc[0].y*inv + b0.y;
    o[2] = acc[1].x*inv + b0.z; o[3] = acc[1].y*inv + b0.w;
    o[4] = acc[2].x*inv + b1.x; o[5] = acc[2].y*inv + b1.y;
    o[6] = acc[3].x*inv + b1.z; o[7] = acc[3].y*inv + b1.w;
    if (do_relu) {
      #pragma unroll
      for (int c = 0; c < 8; c++) o[c] = fmaxf(o[c], 0.f);
    }
    if (houtf) {
      *(float4*)&houtf[i * C + c0]     = make_float4(o[0], o[1], o[2], o[3]);
      *(float4*)&houtf[i * C + c0 + 4] = make_float4(o[4], o[5], o[6], o[7]);
    } else {
      short8 s;
      #pragma unroll
      for (int c = 0; c < 8; c++) s[c] = (short)f2bf(o[c]);
      *(short8*)&houtb[i * C + c0] = s;
    }
  }
}

// ---------------- scorer ----------------

__global__ void gather_pairs(const float* __restrict__ h, const int* __restrict__ tp,
                             const int* __restrict__ fp, float4* __restrict__ out,
                             ushort_t* __restrict__ outbf, int P2) {
  int idx = blockIdx.x * blockDim.x + threadIdx.x;   // float4 index over [2P][256/4]
  if (idx >= P2 * 64) return;
  int r = idx >> 6, c4 = idx & 63;
  int half = P2 >> 1;
  const int* pairs = (r < half) ? tp : fp;
  int rr = (r < half) ? r : r - half;
  int node = pairs[rr * 2 + (c4 >= 32 ? 1 : 0)];
  float4 v = *(const float4*)&h[(size_t)node * C + (c4 & 31) * 4];
  out[idx] = v;
  ushort4 s;
  s.x = f2bf(v.x); s.y = f2bf(v.y); s.z = f2bf(v.z); s.w = f2bf(v.w);
  *(ushort4*)&outbf[(size_t)idx * 4] = s;
}

__global__ __launch_bounds__(256) void probs_loss(
    const float* __restrict__ hid, const float* __restrict__ W2,
    const float* __restrict__ b2, float* __restrict__ probs_out,
    float* __restrict__ lossacc, int rows, int P) {
  __shared__ float red[256];
  int tid = threadIdx.x;
  int r = blockIdx.x * blockDim.x + tid;
  float term = 0.f;
  if (r < rows) {
    const float4* hp = (const float4*)&hid[(size_t)r * C];
    const float4* wp = (const float4*)W2;
    float s = 0.f;
    #pragma unroll
    for (int i = 0; i < 32; i++) {
      float4 h4 = hp[i], w4 = wp[i];
      s += h4.x * w4.x + h4.y * w4.y + h4.z * w4.z + h4.w * w4.w;
    }
    s += b2[0];
    float p = 1.f / (1.f + expf(-s));
    probs_out[r] = p;
    float pcl = fminf(fmaxf(p, 1e-7f), 1.f - 1e-7f);
    term = (r < P) ? logf(pcl) : log1pf(-pcl);
  }
  red[tid] = term;
  __syncthreads();
  #pragma unroll
  for (int off = 128; off >= 1; off >>= 1) {
    if (tid < off) red[tid] += red[tid + off];
    __syncthreads();
  }
  if (tid == 0) atomicAdd(lossacc, red[0]);
}

__global__ void finalize_loss(const float* __restrict__ lossacc, float* __restrict__ out, int rows) {
  out[0] = -lossacc[0] / (float)rows;
}

// ---------------- launch ----------------

extern "C" void kernel_launch(void* const* d_in, const int* in_sizes, int n_in,
                              void* d_out, int out_size, void* d_ws, size_t ws_size,
                              hipStream_t stream) {
  const float* x    = (const float*)d_in[0];
  const int*   ei   = (const int*)d_in[1];
  const int*   tp   = (const int*)d_in[2];
  const int*   fp   = (const int*)d_in[3];
  const float* Wl   = (const float*)d_in[4];
  const float* Wr   = (const float*)d_in[5];
  const float* att  = (const float*)d_in[6];
  const float* bias = (const float*)d_in[7];
  const float* W1   = (const float*)d_in[8];
  const float* b1   = (const float*)d_in[9];
  const float* W2   = (const float*)d_in[10];
  const float* b2   = (const float*)d_in[11];

  int N  = in_sizes[0] / C;    // 50000
  int E  = in_sizes[1] / 2;    // 800000
  int P  = in_sizes[2] / 2;    // 8192
  int ET = E + N;
  int P2 = 2 * P;
  int nb = (N + SCAN_B - 1) / SCAN_B;   // scan blocks (49)

  float* out       = (float*)d_out;
  float* out_pos   = out;                                  // [2P, 2C] (pos then neg)
  float* out_probs = out + (size_t)P2 * 2 * C;
  float* out_loss  = out_probs + P2;

  char* w = (char*)d_ws;
  size_t NCb2 = (size_t)N * C * 2;                         // bf16 [N,C]
  ushort_t* x_bf  = (ushort_t*)w;  w += NCb2;
  ushort_t* xl_bf = (ushort_t*)w;  w += NCb2;
  ushort_t* xr_bf = (ushort_t*)w;  w += NCb2;
  ushort_t* h1_bf = (ushort_t*)w;  w += NCb2;
  float* h1f = (float*)w;          w += (size_t)N * C * 4;
  ushort_t* pairs_bf = (ushort_t*)w; w += (size_t)P2 * 2 * C * 2;
  float* hid = (float*)w;          w += (size_t)P2 * C * 4;
  ushort_t* wcat = (ushort_t*)w;   w += (size_t)2 * 256 * 128 * 2;
  ushort_t* w1t  = (ushort_t*)w;   w += (size_t)128 * 256 * 2;
  int* deg     = (int*)w;  w += (size_t)N * 4;
  int* row_ptr = (int*)w;  w += (size_t)(N + 1) * 4 + 12;  // keep next aligned
  int* pos     = (int*)w;  w += (size_t)ET * 4;
  int* col     = (int*)w;  w += (size_t)ET * 4;
  int* bsums   = (int*)w;  w += (size_t)(nb + 1) * 4 + 8;
  float* lossacc = (float*)w;

  const int tB = 256;
  int total4 = N * C / 4;

  // K0: init + weight prep
  k_init_prep<<<384, tB, 0, stream>>>(deg, lossacc, N, Wl, Wr, W1, wcat, w1t);
  // K1: convert_x + hist
  k_conv_hist<<<(total4 + tB - 1) / tB, tB, 0, stream>>>(x, x_bf, total4, ei, deg, pos, E, ET);

  scan_block<<<nb, SCAN_B, 0, stream>>>(deg, row_ptr, bsums, N);
  scan_sums<<<1, 64, 0, stream>>>(bsums, nb);
  scan_add<<<(N + SCAN_B - 1) / SCAN_B, SCAN_B, 0, stream>>>(row_ptr, bsums, N, nb);

  int gblk = (N + 127) / 128;
  int schunks = (ET + tB - 1) / tB;
  int sxtra = (schunks + 1) / 2;

  // K2: gemm layer-0 ∪ scatter
  k_gemm_scatter<<<dim3(gblk + sxtra, 2), tB, 0, stream>>>(
      x_bf, wcat, N, C, xl_bf, xr_bf, gblk, ei, row_ptr, pos, col, E, ET);

  // layer 0 aggregate (bf16 out + relu)
  gat_aggregate<<<(N * 64 + tB - 1) / tB, tB, 0, stream>>>(
      xl_bf, xr_bf, row_ptr, col, att, bias, nullptr, h1_bf, N, 1);

  // layer 1
  gemm_mfma<<<dim3(gblk, 2), tB, 0, stream>>>(
      h1_bf, wcat + (size_t)256 * 128, N, C, xl_bf, xr_bf, nullptr, nullptr, 0);
  gat_aggregate<<<(N * 64 + tB - 1) / tB, tB, 0, stream>>>(
      xl_bf, xr_bf, row_ptr, col, att + C, bias + C, h1f, nullptr, N, 0);

  gather_pairs<<<(P2 * 64 + tB - 1) / tB, tB, 0, stream>>>(h1f, tp, fp, (float4*)out_pos, pairs_bf, P2);
  gemm_mfma<<<dim3(P2 / 128, 1), tB, 0, stream>>>(
      pairs_bf, w1t, P2, 2 * C, nullptr, nullptr, hid, b1, 1);
  probs_loss<<<(P2 + tB - 1) / tB, tB, 0, stream>>>(hid, W2, b2, out_probs, lossacc, P2, P);
  finalize_loss<<<1, 1, 0, stream>>>(lossacc, out_loss, P2);
}

// Round 10
// 228.091 us; speedup vs baseline: 1.3132x; 1.0349x over previous
//
#include <hip/hip_runtime.h>
#include <math.h>

#define C 128
#define SCAN_B 1024

typedef unsigned short ushort_t;
typedef short short8 __attribute__((ext_vector_type(8)));
typedef float floatx4 __attribute__((ext_vector_type(4)));
typedef float fx2 __attribute__((ext_vector_type(2)));

__device__ __forceinline__ ushort_t f2bf(float x) {
  unsigned u = __float_as_uint(x);
  unsigned r = (u + 0x7FFFu + ((u >> 16) & 1u)) >> 16;
  return (ushort_t)r;
}
__device__ __forceinline__ fx2 bf2f2(unsigned u) {
  fx2 r;
  r.x = __uint_as_float(u << 16);
  r.y = __uint_as_float(u & 0xFFFF0000u);
  return r;
}

// ---------------- K0: init ws + weight prep ----------------

__global__ void k_init_prep(int* __restrict__ deg, float* __restrict__ lossacc,
                            unsigned* __restrict__ done_cnt, int n,
                            const float* __restrict__ Wl, const float* __restrict__ Wr,
                            const float* __restrict__ W1,
                            ushort_t* __restrict__ wcat, ushort_t* __restrict__ w1t) {
  int idx = blockIdx.x * blockDim.x + threadIdx.x;
  if (idx < n) deg[idx] = 0;
  if (idx == 0) { lossacc[0] = 0.f; done_cnt[0] = 0u; }
  const int NCAT = 2 * 256 * 128;
  if (idx < NCAT) {
    int l = idx >> 15;
    int rem = idx & 32767;
    int nn = rem >> 7;
    int k = rem & 127;
    float v = (nn < 128) ? Wl[l * C * C + k * C + nn] : Wr[l * C * C + k * C + (nn - 128)];
    wcat[idx] = f2bf(v);
  } else if (idx < NCAT + 128 * 256) {
    int j = idx - NCAT;
    int nn = j >> 8;
    int k = j & 255;
    w1t[j] = f2bf(W1[k * C + nn]);
  }
}

// ---------------- K1: convert x to bf16 + histogram ----------------

__global__ void k_conv_hist(const float* __restrict__ x, ushort_t* __restrict__ xb, int total4,
                            const int* __restrict__ ei, int* __restrict__ deg,
                            int* __restrict__ pos, int E, int ET) {
  int i = blockIdx.x * blockDim.x + threadIdx.x;
  if (i < total4) {
    float4 v = ((const float4*)x)[i];
    ushort4 s;
    s.x = f2bf(v.x); s.y = f2bf(v.y); s.z = f2bf(v.z); s.w = f2bf(v.w);
    ((ushort4*)xb)[i] = s;
  }
  if (i < ET) {
    int d = (i < E) ? ei[E + i] : (i - E);   // self loop dst = node id
    pos[i] = atomicAdd(&deg[d], 1);
  }
}

// ---------------- scan (block-local; offsets folded at consumers) ----------------

__global__ void scan_block(const int* __restrict__ deg, int* __restrict__ row_ptr,
                           int* __restrict__ bsums, int n) {
  __shared__ int sh[SCAN_B];
  int tid = threadIdx.x;
  int i = blockIdx.x * SCAN_B + tid;
  int v = (i < n) ? deg[i] : 0;
  sh[tid] = v;
  __syncthreads();
  #pragma unroll
  for (int off = 1; off < SCAN_B; off <<= 1) {
    int t = (tid >= off) ? sh[tid - off] : 0;
    __syncthreads();
    sh[tid] += t;
    __syncthreads();
  }
  if (i < n) row_ptr[i] = sh[tid] - v;          // block-local exclusive
  if (tid == SCAN_B - 1) bsums[blockIdx.x] = sh[tid];
}

// exclusive scan of block sums; also writes row_ptr[n] = last chunk's sum
// so that end(wid=n-1) = row_ptr[n] + bsums[n>>10] = total.
__global__ void scan_sums(int* __restrict__ bsums, int nb, int* __restrict__ row_ptr, int n) {
  int lane = threadIdx.x;
  int v = (lane < nb) ? bsums[lane] : 0;
  int orig = v;
  #pragma unroll
  for (int off = 1; off < 64; off <<= 1) {
    int t = __shfl_up(v, off);
    if (lane >= off) v += t;
  }
  if (lane < nb) bsums[lane] = v - orig;        // exclusive
  if (lane == nb - 1) row_ptr[n] = orig;        // last chunk's local total
}

// ---------------- bf16 MFMA GEMM body (shared) ----------------

__device__ __forceinline__ void gemm_body(
    const ushort_t* __restrict__ A, const ushort_t* __restrict__ Bt,
    int M, int K,
    ushort_t* __restrict__ outb0, ushort_t* __restrict__ outb1,
    float* __restrict__ outf, const float* __restrict__ bias, int do_relu,
    int bx, int by) {
  int tid = threadIdx.x;
  int wave = tid >> 6, lane = tid & 63;
  int wm = (wave >> 1) * 64, wn = (wave & 1) * 64;
  int m_base = bx * 128 + wm;
  int lrow = lane & 15, lkg = lane >> 4;

  floatx4 acc[4][4];
  #pragma unroll
  for (int mi = 0; mi < 4; mi++)
    #pragma unroll
    for (int ni = 0; ni < 4; ni++)
      acc[mi][ni] = (floatx4){0.f, 0.f, 0.f, 0.f};

  const int ksteps = K >> 5;
  for (int ks = 0; ks < ksteps; ks++) {
    int koff = ks * 32 + lkg * 8;
    short8 af[4], bfr[4];
    #pragma unroll
    for (int mi = 0; mi < 4; mi++) {
      int gm = m_base + mi * 16 + lrow;
      gm = (gm < M) ? gm : (M - 1);
      af[mi] = *(const short8*)&A[(size_t)gm * K + koff];
    }
    #pragma unroll
    for (int ni = 0; ni < 4; ni++) {
      int gn = by * 128 + wn + ni * 16 + lrow;
      bfr[ni] = *(const short8*)&Bt[(size_t)gn * K + koff];
    }
    #pragma unroll
    for (int mi = 0; mi < 4; mi++)
      #pragma unroll
      for (int ni = 0; ni < 4; ni++)
        acc[mi][ni] = __builtin_amdgcn_mfma_f32_16x16x32_bf16(af[mi], bfr[ni], acc[mi][ni], 0, 0, 0);
  }

  ushort_t* outb = (by == 0) ? outb0 : outb1;
  #pragma unroll
  for (int mi = 0; mi < 4; mi++) {
    #pragma unroll
    for (int r = 0; r < 4; r++) {
      int gm = m_base + mi * 16 + lkg * 4 + r;
      if (gm >= M) continue;
      #pragma unroll
      for (int ni = 0; ni < 4; ni++) {
        int nl = wn + ni * 16 + lrow;
        float v = acc[mi][ni][r];
        if (outf) {
          if (bias) v += bias[nl];
          if (do_relu) v = fmaxf(v, 0.f);
          outf[(size_t)gm * 128 + nl] = v;
        } else {
          outb[(size_t)gm * 128 + nl] = f2bf(v);
        }
      }
    }
  }
}

__global__ __launch_bounds__(256) void gemm_mfma(
    const ushort_t* __restrict__ A, const ushort_t* __restrict__ Bt,
    int M, int K,
    ushort_t* __restrict__ outb0, ushort_t* __restrict__ outb1,
    float* __restrict__ outf, const float* __restrict__ bias, int do_relu) {
  gemm_body(A, Bt, M, K, outb0, outb1, outf, bias, do_relu, blockIdx.x, blockIdx.y);
}

// ---------------- K2: gemm layer-0 ∪ scatter (offset-folded, padded col) ----------------

__global__ __launch_bounds__(256) void k_gemm_scatter(
    const ushort_t* __restrict__ A, const ushort_t* __restrict__ Bt,
    int M, int K,
    ushort_t* __restrict__ outb0, ushort_t* __restrict__ outb1, int gb,
    const int* __restrict__ ei, const int* __restrict__ row_ptr,
    const int* __restrict__ bsums, const int* __restrict__ pos,
    int* __restrict__ col, int E, int ET, int ETp) {
  int bx = blockIdx.x;
  if (bx < gb) {
    gemm_body(A, Bt, M, K, outb0, outb1, nullptr, nullptr, 0, bx, blockIdx.y);
  } else {
    int chunk = (bx - gb) * 2 + blockIdx.y;
    int e = chunk * 256 + threadIdx.x;
    if (e < ET) {
      int s = (e < E) ? ei[e] : (e - E);
      int d = (e < E) ? ei[E + e] : (e - E);
      col[row_ptr[d] + bsums[d >> 10] + pos[e]] = s;
    } else if (e < ETp) {
      col[e] = 0;                      // padding: safe dummy index
    }
  }
}

// ---------------- GATv2 fused edge softmax + aggregation ----------------
// One wave per dst node; 4 groups x 16 lanes x 2 edges/iter.
// col is padded (+8 zeros) -> unconditional loads; exp2-domain logits.

__global__ __launch_bounds__(256) void gat_aggregate(
    const ushort_t* __restrict__ xl, const ushort_t* __restrict__ xr,
    const int* __restrict__ row_ptr, const int* __restrict__ bsums,
    const int* __restrict__ col,
    const float* __restrict__ att, const float* __restrict__ bias,
    float* __restrict__ houtf, ushort_t* __restrict__ houtb,
    int n, int do_relu) {
  int wid = (int)((blockIdx.x * (size_t)blockDim.x + threadIdx.x) >> 6);
  int lane = threadIdx.x & 63;
  if (wid >= n) return;
  int g = lane >> 4, p = lane & 15;
  int c0 = p * 8;
  const size_t i = wid;

  fx2 xri[4], av[4];
  {
    uint4 ur = *(const uint4*)&xr[i * C + c0];
    xri[0] = bf2f2(ur.x); xri[1] = bf2f2(ur.y);
    xri[2] = bf2f2(ur.z); xri[3] = bf2f2(ur.w);
    float4 a0 = *(const float4*)&att[c0];
    float4 a1 = *(const float4*)&att[c0 + 4];
    const float L2E = 1.44269504088896f;     // exp2-domain logits
    av[0] = (fx2){a0.x * L2E, a0.y * L2E}; av[1] = (fx2){a0.z * L2E, a0.w * L2E};
    av[2] = (fx2){a1.x * L2E, a1.y * L2E}; av[3] = (fx2){a1.z * L2E, a1.w * L2E};
  }

  int beg = row_ptr[wid] + bsums[wid >> 10];
  int end = row_ptr[wid + 1] + bsums[(wid + 1) >> 10];
  float denom = 0.f;
  fx2 acc[4];
  #pragma unroll
  for (int q = 0; q < 4; q++) acc[q] = (fx2){0.f, 0.f};

  for (int base = beg; base < end; base += 8) {
    int e0 = base + g;
    int e1 = e0 + 4;
    int j0 = col[e0];                       // unconditional: col padded
    int j1 = col[e1];
    uint4 r0 = *(const uint4*)&xl[((size_t)j0 << 7) + c0];
    uint4 r1 = *(const uint4*)&xl[((size_t)j1 << 7) + c0];
    fx2 x0[4], x1[4];
    x0[0] = bf2f2(r0.x); x0[1] = bf2f2(r0.y); x0[2] = bf2f2(r0.z); x0[3] = bf2f2(r0.w);
    x1[0] = bf2f2(r1.x); x1[1] = bf2f2(r1.y); x1[2] = bf2f2(r1.z); x1[3] = bf2f2(r1.w);

    fx2 d0 = (fx2){0.f, 0.f}, d1 = (fx2){0.f, 0.f};
    #pragma unroll
    for (int q = 0; q < 4; q++) {
      fx2 z0 = x0[q] + xri[q];
      fx2 z1 = x1[q] + xri[q];
      z0 = __builtin_elementwise_max(z0, z0 * 0.2f);
      z1 = __builtin_elementwise_max(z1, z1 * 0.2f);
      d0 = __builtin_elementwise_fma(z0, av[q], d0);
      d1 = __builtin_elementwise_fma(z1, av[q], d1);
    }
    float p0 = d0.x + d0.y;
    float p1 = d1.x + d1.y;
    #pragma unroll
    for (int off = 1; off <= 8; off <<= 1) {
      p0 += __shfl_xor(p0, off);
      p1 += __shfl_xor(p1, off);
    }
    float pe0 = (e0 < end) ? __builtin_amdgcn_exp2f(p0) : 0.f;
    float pe1 = (e1 < end) ? __builtin_amdgcn_exp2f(p1) : 0.f;
    denom += pe0 + pe1;
    fx2 v0 = (fx2){pe0, pe0}, v1 = (fx2){pe1, pe1};
    #pragma unroll
    for (int q = 0; q < 4; q++) {
      acc[q] = __builtin_elementwise_fma(v0, x0[q], acc[q]);
      acc[q] = __builtin_elementwise_fma(v1, x1[q], acc[q]);
    }
  }

  #pragma unroll
  for (int off = 16; off <= 32; off <<= 1) {
    denom += __shfl_xor(denom, off);
    #pragma unroll
    for (int q = 0; q < 4; q++) {
      acc[q].x += __shfl_xor(acc[q].x, off);
      acc[q].y += __shfl_xor(acc[q].y, off);
    }
  }

  if (g == 0) {
    float inv = 1.f / denom;            // degree >= 1 via self loop
    float4 b0 = *(const float4*)&bias[c0];
    float4 b1 = *(const float4*)&bias[c0 + 4];
    float o[8];
    o[0] = acc[0].x*inv + b0.x; o[1] = acc[0].y*inv + b0.y;
    o[2] = acc[1].x*inv + b0.z; o[3] = acc[1].y*inv + b0.w;
    o[4] = acc[2].x*inv + b1.x; o[5] = acc[2].y*inv + b1.y;
    o[6] = acc[3].x*inv + b1.z; o[7] = acc[3].y*inv + b1.w;
    if (do_relu) {
      #pragma unroll
      for (int c = 0; c < 8; c++) o[c] = fmaxf(o[c], 0.f);
    }
    if (houtf) {
      *(float4*)&houtf[i * C + c0]     = make_float4(o[0], o[1], o[2], o[3]);
      *(float4*)&houtf[i * C + c0 + 4] = make_float4(o[4], o[5], o[6], o[7]);
    } else {
      short8 s;
      #pragma unroll
      for (int c = 0; c < 8; c++) s[c] = (short)f2bf(o[c]);
      *(short8*)&houtb[i * C + c0] = s;
    }
  }
}

// ---------------- scorer GEMM with fused pair-gather ----------------
// A rows gathered from h1f via tp/fp (f32 -> bf16 in-register); wn==0 waves
// also emit the f32 concat rows to out_pos (d_out). M = P2 (multiple of 128),
// K = 256, N = 128. hid = relu(A @ W1 + b1).

__global__ __launch_bounds__(256) void gemm_scorer(
    const float* __restrict__ h, const int* __restrict__ tp, const int* __restrict__ fp,
    const ushort_t* __restrict__ w1t, float* __restrict__ out_pos,
    float* __restrict__ hid, const float* __restrict__ b1, int P2) {
  int tid = threadIdx.x;
  int wave = tid >> 6, lane = tid & 63;
  int wm = (wave >> 1) * 64, wn = (wave & 1) * 64;
  int m_base = blockIdx.x * 128 + wm;
  int lrow = lane & 15, lkg = lane >> 4;
  int half = P2 >> 1;
  bool emit = (wn == 0);

  int n0[4], n1[4];
  #pragma unroll
  for (int mi = 0; mi < 4; mi++) {
    int gm = m_base + mi * 16 + lrow;
    const int* pr = (gm < half) ? &tp[(size_t)gm * 2] : &fp[(size_t)(gm - half) * 2];
    n0[mi] = pr[0];
    n1[mi] = pr[1];
  }

  floatx4 acc[4][4];
  #pragma unroll
  for (int mi = 0; mi < 4; mi++)
    #pragma unroll
    for (int ni = 0; ni < 4; ni++)
      acc[mi][ni] = (floatx4){0.f, 0.f, 0.f, 0.f};

  #pragma unroll
  for (int ks = 0; ks < 8; ks++) {
    int koff = ks * 32 + lkg * 8;        // 0..248; ks<4 -> first node
    int chan = koff & 127;
    short8 af[4], bfr[4];
    #pragma unroll
    for (int mi = 0; mi < 4; mi++) {
      int node = (ks < 4) ? n0[mi] : n1[mi];
      const float* src = &h[(size_t)node * C + chan];
      float4 lo = *(const float4*)src;
      float4 hi = *(const float4*)(src + 4);
      if (emit) {
        int gm = m_base + mi * 16 + lrow;
        *(float4*)&out_pos[(size_t)gm * 256 + koff]     = lo;
        *(float4*)&out_pos[(size_t)gm * 256 + koff + 4] = hi;
      }
      short8 a;
      a[0] = (short)f2bf(lo.x); a[1] = (short)f2bf(lo.y);
      a[2] = (short)f2bf(lo.z); a[3] = (short)f2bf(lo.w);
      a[4] = (short)f2bf(hi.x); a[5] = (short)f2bf(hi.y);
      a[6] = (short)f2bf(hi.z); a[7] = (short)f2bf(hi.w);
      af[mi] = a;
    }
    #pragma unroll
    for (int ni = 0; ni < 4; ni++) {
      int gn = wn + ni * 16 + lrow;
      bfr[ni] = *(const short8*)&w1t[(size_t)gn * 256 + koff];
    }
    #pragma unroll
    for (int mi = 0; mi < 4; mi++)
      #pragma unroll
      for (int ni = 0; ni < 4; ni++)
        acc[mi][ni] = __builtin_amdgcn_mfma_f32_16x16x32_bf16(af[mi], bfr[ni], acc[mi][ni], 0, 0, 0);
  }

  #pragma unroll
  for (int mi = 0; mi < 4; mi++) {
    #pragma unroll
    for (int r = 0; r < 4; r++) {
      int gm = m_base + mi * 16 + lkg * 4 + r;
      #pragma unroll
      for (int ni = 0; ni < 4; ni++) {
        int nl = wn + ni * 16 + lrow;
        float v = acc[mi][ni][r] + b1[nl];
        v = fmaxf(v, 0.f);
        hid[(size_t)gm * 128 + nl] = v;
      }
    }
  }
}

// ---------------- probs + loss (finalize fused via completion counter) ----------------

__global__ __launch_bounds__(256) void probs_loss(
    const float* __restrict__ hid, const float* __restrict__ W2,
    const float* __restrict__ b2, float* __restrict__ probs_out,
    float* __restrict__ lossacc, unsigned* __restrict__ done_cnt,
    float* __restrict__ out_loss, int rows, int P) {
  __shared__ float red[256];
  int tid = threadIdx.x;
  int r = blockIdx.x * blockDim.x + tid;
  float term = 0.f;
  if (r < rows) {
    const float4* hp = (const float4*)&hid[(size_t)r * C];
    const float4* wp = (const float4*)W2;
    float s = 0.f;
    #pragma unroll
    for (int i = 0; i < 32; i++) {
      float4 h4 = hp[i], w4 = wp[i];
      s += h4.x * w4.x + h4.y * w4.y + h4.z * w4.z + h4.w * w4.w;
    }
    s += b2[0];
    float p = 1.f / (1.f + expf(-s));
    probs_out[r] = p;
    float pcl = fminf(fmaxf(p, 1e-7f), 1.f - 1e-7f);
    term = (r < P) ? logf(pcl) : log1pf(-pcl);
  }
  red[tid] = term;
  __syncthreads();
  #pragma unroll
  for (int off = 128; off >= 1; off >>= 1) {
    if (tid < off) red[tid] += red[tid + off];
    __syncthreads();
  }
  if (tid == 0) {
    atomicAdd(lossacc, red[0]);
    __threadfence();
    unsigned prev = atomicAdd(done_cnt, 1u);
    if (prev == gridDim.x - 1) {
      float total = atomicAdd(lossacc, 0.f);    // coherent read
      out_loss[0] = -total / (float)rows;
    }
  }
}

// ---------------- launch ----------------

extern "C" void kernel_launch(void* const* d_in, const int* in_sizes, int n_in,
                              void* d_out, int out_size, void* d_ws, size_t ws_size,
                              hipStream_t stream) {
  const float* x    = (const float*)d_in[0];
  const int*   ei   = (const int*)d_in[1];
  const int*   tp   = (const int*)d_in[2];
  const int*   fp   = (const int*)d_in[3];
  const float* Wl   = (const float*)d_in[4];
  const float* Wr   = (const float*)d_in[5];
  const float* att  = (const float*)d_in[6];
  const float* bias = (const float*)d_in[7];
  const float* W1   = (const float*)d_in[8];
  const float* b1   = (const float*)d_in[9];
  const float* W2   = (const float*)d_in[10];
  const float* b2   = (const float*)d_in[11];

  int N  = in_sizes[0] / C;    // 50000
  int E  = in_sizes[1] / 2;    // 800000
  int P  = in_sizes[2] / 2;    // 8192
  int ET = E + N;
  int ETp = ET + 8;            // padded col
  int P2 = 2 * P;
  int nb = (N + SCAN_B - 1) / SCAN_B;   // scan blocks (49)

  float* out       = (float*)d_out;
  float* out_pos   = out;                                  // [2P, 2C] (pos then neg)
  float* out_probs = out + (size_t)P2 * 2 * C;
  float* out_loss  = out_probs + P2;

  char* w = (char*)d_ws;
  size_t NCb2 = (size_t)N * C * 2;                         // bf16 [N,C]
  ushort_t* x_bf  = (ushort_t*)w;  w += NCb2;
  ushort_t* xl_bf = (ushort_t*)w;  w += NCb2;
  ushort_t* xr_bf = (ushort_t*)w;  w += NCb2;
  ushort_t* h1_bf = (ushort_t*)w;  w += NCb2;
  float* h1f = (float*)w;          w += (size_t)N * C * 4;
  float* hid = (float*)w;          w += (size_t)P2 * C * 4;
  ushort_t* wcat = (ushort_t*)w;   w += (size_t)2 * 256 * 128 * 2;
  ushort_t* w1t  = (ushort_t*)w;   w += (size_t)128 * 256 * 2;
  int* deg     = (int*)w;  w += (size_t)N * 4;
  int* row_ptr = (int*)w;  w += (size_t)(N + 1) * 4 + 12;  // keep next aligned
  int* pos     = (int*)w;  w += (size_t)ET * 4;
  int* col     = (int*)w;  w += (size_t)ETp * 4;
  int* bsums   = (int*)w;  w += (size_t)(nb + 1) * 4 + 8;
  float* lossacc = (float*)w;  w += 16;
  unsigned* done_cnt = (unsigned*)w;

  const int tB = 256;
  int total4 = N * C / 4;

  // K0: init + weight prep
  k_init_prep<<<384, tB, 0, stream>>>(deg, lossacc, done_cnt, N, Wl, Wr, W1, wcat, w1t);
  // K1: convert_x + hist
  k_conv_hist<<<(total4 + tB - 1) / tB, tB, 0, stream>>>(x, x_bf, total4, ei, deg, pos, E, ET);

  scan_block<<<nb, SCAN_B, 0, stream>>>(deg, row_ptr, bsums, N);
  scan_sums<<<1, 64, 0, stream>>>(bsums, nb, row_ptr, N);

  int gblk = (N + 127) / 128;
  int schunks = (ETp + tB - 1) / tB;
  int sxtra = (schunks + 1) / 2;

  // K2: gemm layer-0 ∪ scatter (+ padding)
  k_gemm_scatter<<<dim3(gblk + sxtra, 2), tB, 0, stream>>>(
      x_bf, wcat, N, C, xl_bf, xr_bf, gblk, ei, row_ptr, bsums, pos, col, E, ET, ETp);

  // layer 0 aggregate (bf16 out + relu)
  gat_aggregate<<<(N * 64 + tB - 1) / tB, tB, 0, stream>>>(
      xl_bf, xr_bf, row_ptr, bsums, col, att, bias, nullptr, h1_bf, N, 1);

  // layer 1
  gemm_mfma<<<dim3(gblk, 2), tB, 0, stream>>>(
      h1_bf, wcat + (size_t)256 * 128, N, C, xl_bf, xr_bf, nullptr, nullptr, 0);
  gat_aggregate<<<(N * 64 + tB - 1) / tB, tB, 0, stream>>>(
      xl_bf, xr_bf, row_ptr, bsums, col, att + C, bias + C, h1f, nullptr, N, 0);

  // scorer: fused gather + GEMM, then probs/loss (+finalize)
  gemm_scorer<<<P2 / 128, tB, 0, stream>>>(h1f, tp, fp, w1t, out_pos, hid, b1, P2);
  probs_loss<<<(P2 + tB - 1) / tB, tB, 0, stream>>>(
      hid, W2, b2, out_probs, lossacc, done_cnt, out_loss, P2, P);
}